// Round 6
// baseline (401.139 us; speedup 1.0000x reference)
//
#include <hip/hip_runtime.h>
#include <hip/hip_bf16.h>
#include <stdint.h>

#define MARGIN   0.5f
#define POS_THR  (1.0f - 1e-5f)

typedef __attribute__((ext_vector_type(8))) short  short8;
typedef __attribute__((ext_vector_type(4))) float  f32x4;

#define BM 128
#define BN 128
#define BK 32
#define NPANEL_SHIFT 7   // BN = 128
#define NSLOTS 256       // misc[0..255] partial sums, misc[256] = stale pos
#define MAXN_HIST 8192   // LDS histogram capacity in prep

// ---------- helpers ----------
__device__ __forceinline__ ushort f2bf_rne(float x) {
  uint32_t u = __float_as_uint(x);
  u += 0x7fffu + ((u >> 16) & 1u);
  return (ushort)(u >> 16);
}

__device__ __forceinline__ void async_load16(const ushort* g, ushort* l) {
  // width-16 global->LDS DMA; LDS dest = wave-uniform base + lane*16B
  __builtin_amdgcn_global_load_lds(
      (__attribute__((address_space(1))) void*)(const_cast<ushort*>(g)),
      (__attribute__((address_space(3))) void*)(l),
      16, 0, 0);
}

// ---------- prep: convert blocks + ONE histogram block (fused count) ----------
__global__ void prep_kernel(const float* __restrict__ src, ushort* __restrict__ dst,
                            const int* __restrict__ new_idx,
                            int* __restrict__ cnt, int* __restrict__ flags,
                            float* __restrict__ misc, int* __restrict__ done,
                            int total8, int n, int npanel, int n_new, int convBlocks) {
  __shared__ int hcnt[MAXN_HIST];
  __shared__ int hflag[MAXN_HIST / BN];
  const int tid = threadIdx.x;
  if ((int)blockIdx.x < convBlocks) {
    int i = blockIdx.x * blockDim.x + tid;
    if (i < total8) {
      const float4* s4 = reinterpret_cast<const float4*>(src);
      float4 a = s4[i * 2], b = s4[i * 2 + 1];
      short8 o;
      o[0] = (short)f2bf_rne(a.x); o[1] = (short)f2bf_rne(a.y);
      o[2] = (short)f2bf_rne(a.z); o[3] = (short)f2bf_rne(a.w);
      o[4] = (short)f2bf_rne(b.x); o[5] = (short)f2bf_rne(b.y);
      o[6] = (short)f2bf_rne(b.z); o[7] = (short)f2bf_rne(b.w);
      reinterpret_cast<short8*>(dst)[i] = o;
    }
    return;
  }
  // histogram block (n <= MAXN_HIST guaranteed for this problem)
  for (int i = tid; i < n; i += blockDim.x) hcnt[i] = 0;
  for (int i = tid; i < npanel; i += blockDim.x) hflag[i] = 0;
  __syncthreads();
  for (int i = tid; i < n_new; i += blockDim.x) atomicAdd(&hcnt[new_idx[i]], 1);
  __syncthreads();
  for (int i = tid; i < n; i += blockDim.x) {
    int c = hcnt[i];
    cnt[i] = c;
    if (c) atomicOr(&hflag[i >> NPANEL_SHIFT], 1);
  }
  __syncthreads();
  for (int i = tid; i < npanel; i += blockDim.x) flags[i] = hflag[i];
  for (int i = tid; i < NSLOTS + 1; i += blockDim.x) misc[i] = 0.f;
  if (tid == 0) *done = 0;
}

// ---------- main fused GEMM + masked-reduction + last-block finalize ----------
// sim = F*F^T (bf16 MFMA 16x16x32, fp32 accum), 128x128 tile, 4 waves (2x2),
// 3-buffer ring, counted vmcnt(4) + raw s_barrier per kstep.
// K-loop schedule = R4's measured-best: sched_barrier(0) pins prefetch-first,
// lgkmcnt(0)+sched_barrier(0) before the MFMA cluster (R5's "let the compiler
// float it" variant measured 20% SLOWER — keep this pinned).
__global__ __launch_bounds__(256) void simloss_kernel(
    const ushort* __restrict__ fb, const int* __restrict__ target,
    const int* __restrict__ cnt, const int* __restrict__ colHasNew,
    float* __restrict__ misc, int* __restrict__ done, float* __restrict__ out,
    int d, int n, int n_new, float alpha) {
  __shared__ __align__(16) ushort Als[3][BM * BK];
  __shared__ __align__(16) ushort Bls[3][BN * BK];
  __shared__ int   t_row[BM];
  __shared__ int   t_col[BN];
  __shared__ float cw_col[BN];
  __shared__ float red[4];
  __shared__ int   lastFlag;

  const int tid = threadIdx.x;
  const int rowBase = blockIdx.y * BM;
  const int colBase = blockIdx.x * BN;
  const int lane = tid & 63;
  const int wid  = tid >> 6;

  // old-row block over a panel with no new cols contributes nothing (block-uniform)
  const bool skip = (rowBase >= n_new) && (colHasNew[blockIdx.x] == 0);

  if (!skip) {
    if (tid < BM) t_row[tid] = target[rowBase + tid];
    if (tid < BN) {
      t_col[tid]  = target[colBase + tid];
      cw_col[tid] = (float)cnt[colBase + tid];
    }

    const int wr  = wid >> 1;
    const int wc  = wid & 1;
    const int l15 = lane & 15;
    const int kb  = lane >> 4;

    // staging: 512 16B-chunks per 128x32 tile; wave w issues chunks (2w+cc)*64+lane;
    // global source pre-swizzled with involution slot^=(row>>1)&3 (rule #21)
    const int ch0 = (wid * 2 + 0) * 64 + lane;
    const int ch1 = (wid * 2 + 1) * 64 + lane;
    const int r0 = ch0 >> 2, kq0 = (ch0 & 3) ^ ((ch0 >> 3) & 3);
    const int r1 = ch1 >> 2, kq1 = (ch1 & 3) ^ ((ch1 >> 3) & 3);
    const ushort* gA0 = fb + (size_t)(rowBase + r0) * d + kq0 * 8;
    const ushort* gA1 = fb + (size_t)(rowBase + r1) * d + kq1 * 8;
    const ushort* gB0 = fb + (size_t)(colBase + r0) * d + kq0 * 8;
    const ushort* gB1 = fb + (size_t)(colBase + r1) * d + kq1 * 8;
    const int lo0 = (wid * 2 + 0) * 512;
    const int lo1 = (wid * 2 + 1) * 512;

    f32x4 acc[4][4] = {};

    int aoff[4], boff[4];
#pragma unroll
    for (int m = 0; m < 4; ++m) {
      int row = wr * 64 + m * 16 + l15;
      aoff[m] = row * 32 + ((kb ^ ((row >> 1) & 3)) * 8);
    }
#pragma unroll
    for (int nf = 0; nf < 4; ++nf) {
      int row = wc * 64 + nf * 16 + l15;
      boff[nf] = row * 32 + ((kb ^ ((row >> 1) & 3)) * 8);
    }

    // drain metadata loads so manual vmcnt counts are exact
    asm volatile("s_waitcnt vmcnt(0) lgkmcnt(0)" ::: "memory");
    __builtin_amdgcn_sched_barrier(0);

    // prologue: stage tiles 0 and 1 (8 loads in flight)
    async_load16(gA0, &Als[0][lo0]);
    async_load16(gA1, &Als[0][lo1]);
    async_load16(gB0, &Bls[0][lo0]);
    async_load16(gB1, &Bls[0][lo1]);
    const int nk = d / BK;
    if (nk > 1) {
      async_load16(gA0 + BK, &Als[1][lo0]);
      async_load16(gA1 + BK, &Als[1][lo1]);
      async_load16(gB0 + BK, &Bls[1][lo0]);
      async_load16(gB1 + BK, &Bls[1][lo1]);
    }

    int cur = 0;
    for (int t = 0; t < nk; ++t) {
      if (t == nk - 1) asm volatile("s_waitcnt vmcnt(0)" ::: "memory");
      else             asm volatile("s_waitcnt vmcnt(4)" ::: "memory");
      __builtin_amdgcn_s_barrier();
      __builtin_amdgcn_sched_barrier(0);

      if (t + 2 < nk) {
        int nxt = cur + 2; if (nxt >= 3) nxt -= 3;
        int ko = (t + 2) * BK;
        async_load16(gA0 + ko, &Als[nxt][lo0]);
        async_load16(gA1 + ko, &Als[nxt][lo1]);
        async_load16(gB0 + ko, &Bls[nxt][lo0]);
        async_load16(gB1 + ko, &Bls[nxt][lo1]);
      }

      short8 afr[4], bfr[4];
#pragma unroll
      for (int m = 0; m < 4; ++m)
        afr[m] = *reinterpret_cast<const short8*>(&Als[cur][aoff[m]]);
#pragma unroll
      for (int nf = 0; nf < 4; ++nf)
        bfr[nf] = *reinterpret_cast<const short8*>(&Bls[cur][boff[nf]]);
      asm volatile("s_waitcnt lgkmcnt(0)" ::: "memory");
      __builtin_amdgcn_sched_barrier(0);

      // swapped operands: acc row = rowBase+wr*64+m*16+l15 (lane-fixed),
      // col = colBase+wc*64+nf*16+kb*4+q
#pragma unroll
      for (int m = 0; m < 4; ++m)
#pragma unroll
        for (int nf = 0; nf < 4; ++nf)
          acc[m][nf] = __builtin_amdgcn_mfma_f32_16x16x32_bf16(bfr[nf], afr[m], acc[m][nf], 0, 0, 0);

      cur = (cur + 1 == 3) ? 0 : cur + 1;
    }

    // ---- epilogue: per-lane masked fold -> block scalar ----
    const float beta = 1.0f - alpha;
    const int wr2 = wid >> 1, wc2 = wid & 1, l15b = lane & 15, kb2 = lane >> 4;
    int tc_r[4][4]; float cw_r[4][4];
#pragma unroll
    for (int nf = 0; nf < 4; ++nf)
#pragma unroll
      for (int q = 0; q < 4; ++q) {
        int cl = wc2 * 64 + nf * 16 + kb2 * 4 + q;
        tc_r[nf][q] = t_col[cl];
        cw_r[nf][q] = cw_col[cl];
      }

    const int  stale_row = n_new - 1;
    const bool blk_stale = (stale_row >= rowBase) && (stale_row < rowBase + BM);
    const int  srl = stale_row - rowBase;

    float c = 0.f;
#pragma unroll
    for (int m = 0; m < 4; ++m) {
      int rl = wr2 * 64 + m * 16 + l15b;
      int r  = rowBase + rl;
      int tr = t_row[rl];
      bool isnew = (r < n_new);
      float p = 0.f, ng = 0.f;
#pragma unroll
      for (int nf = 0; nf < 4; ++nf)
#pragma unroll
        for (int q = 0; q < 4; ++q) {
          float s = acc[m][nf][q];
          bool same = (tr == tc_r[nf][q]);
          if (isnew) {
            if (same && s < POS_THR)  p  += cw_r[nf][q] * (1.0f - s);
            if (!same && s > MARGIN)  ng += s;
          } else {
            if (!same && s > MARGIN)  ng += cw_r[nf][q] * s;
          }
        }
      if (blk_stale && wr2 == (srl >> 6) && m == ((srl >> 4) & 3)) {
        float pr = p;
        pr += __shfl_xor(pr, 16); pr += __shfl_xor(pr, 32);
        if (lane < 16 && rl == srl) atomicAdd(&misc[NSLOTS], pr);
      }
      c += isnew ? fmaf(alpha, p, beta * ng) : beta * ng;
    }
#pragma unroll
    for (int off = 32; off; off >>= 1) c += __shfl_xor(c, off);
    if (lane == 0) red[wid] = c;
    __syncthreads();
    if (tid == 0)
      atomicAdd(&misc[(blockIdx.y * gridDim.x + blockIdx.x) & (NSLOTS - 1)],
                red[0] + red[1] + red[2] + red[3]);
  }

  // ---- fused finalize: last-finishing block reduces misc -> out ----
  __threadfence();
  const int nblk = gridDim.x * gridDim.y;
  if (tid == 0) lastFlag = (atomicAdd(done, 1) == nblk - 1) ? 1 : 0;
  __syncthreads();
  if (lastFlag) {
    __threadfence();
    float c = (tid < NSLOTS)
        ? __hip_atomic_load(&misc[tid], __ATOMIC_RELAXED, __HIP_MEMORY_SCOPE_AGENT)
        : 0.f;
#pragma unroll
    for (int off = 32; off; off >>= 1) c += __shfl_xor(c, off);
    if (lane == 0) red[wid] = c;
    __syncthreads();
    if (tid == 0) {
      float stale = __hip_atomic_load(&misc[NSLOTS], __ATOMIC_RELAXED,
                                      __HIP_MEMORY_SCOPE_AGENT);
      out[0] = (red[0] + red[1] + red[2] + red[3] +
                (float)(n - n_new) * alpha * stale) / (float)n;
    }
  }
}

// ---------- launch ----------
extern "C" void kernel_launch(void* const* d_in, const int* in_sizes, int n_in,
                              void* d_out, int out_size, void* d_ws, size_t ws_size,
                              hipStream_t stream) {
  const float* feature = (const float*)d_in[0];
  const int*   target  = (const int*)d_in[1];
  const int*   new_idx = (const int*)d_in[2];

  const int n     = in_sizes[1];
  const int d     = in_sizes[0] / n;
  const int n_new = in_sizes[2];
  const int n_old = (n_in > 3) ? in_sizes[3] : 0;
  const float alpha = (n_old != 0) ? 0.9f : 0.5f;
  const int npanel = n / BN;

  auto al = [](size_t x) { return (x + 255) & ~(size_t)255; };
  char* ws = (char*)d_ws;
  ushort* fb    = (ushort*)ws;
  size_t  off   = al((size_t)n * d * sizeof(ushort));
  int*    cnt   = (int*)(ws + off);   off += al((size_t)n * sizeof(int));
  int*    flags = (int*)(ws + off);   off += al((size_t)npanel * sizeof(int));
  float*  misc  = (float*)(ws + off); off += al((size_t)(NSLOTS + 1) * sizeof(float));
  int*    done  = (int*)(ws + off);

  int total8 = (n * d) / 8;
  int convBlocks = (total8 + 255) / 256;
  prep_kernel<<<convBlocks + 1, 256, 0, stream>>>(feature, fb, new_idx, cnt, flags,
                                                  misc, done, total8, n, npanel,
                                                  n_new, convBlocks);

  dim3 grid(n / BN, n / BM);
  simloss_kernel<<<grid, 256, 0, stream>>>(fb, target, cnt, flags, misc, done,
                                           (float*)d_out, d, n, n_new, alpha);
}

// Round 7
// 125.772 us; speedup vs baseline: 3.1894x; 3.1894x over previous
//
#include <hip/hip_runtime.h>
#include <hip/hip_bf16.h>
#include <stdint.h>

#define MARGIN   0.5f
#define POS_THR  (1.0f - 1e-5f)

typedef __attribute__((ext_vector_type(8))) short  short8;
typedef __attribute__((ext_vector_type(4))) float  f32x4;

#define BM 128
#define BN 128
#define BK 32
#define NPANEL_SHIFT 7   // BN = 128
#define NSLOTS 256       // misc[0..255] partial sums, misc[256] = stale pos
#define MAXN_HIST 8192   // LDS histogram capacity in prep

// ---------- helpers ----------
__device__ __forceinline__ ushort f2bf_rne(float x) {
  uint32_t u = __float_as_uint(x);
  u += 0x7fffu + ((u >> 16) & 1u);
  return (ushort)(u >> 16);
}

__device__ __forceinline__ void async_load16(const ushort* g, ushort* l) {
  // width-16 global->LDS DMA; LDS dest = wave-uniform base + lane*16B
  __builtin_amdgcn_global_load_lds(
      (__attribute__((address_space(1))) void*)(const_cast<ushort*>(g)),
      (__attribute__((address_space(3))) void*)(l),
      16, 0, 0);
}

// ---------- prep: convert blocks + ONE histogram block (fused count) ----------
__global__ void prep_kernel(const float* __restrict__ src, ushort* __restrict__ dst,
                            const int* __restrict__ new_idx,
                            int* __restrict__ cnt, int* __restrict__ flags,
                            float* __restrict__ misc,
                            int total8, int n, int npanel, int n_new, int convBlocks) {
  __shared__ int hcnt[MAXN_HIST];
  __shared__ int hflag[MAXN_HIST / BN];
  const int tid = threadIdx.x;
  if ((int)blockIdx.x < convBlocks) {
    int i = blockIdx.x * blockDim.x + tid;
    if (i < total8) {
      const float4* s4 = reinterpret_cast<const float4*>(src);
      float4 a = s4[i * 2], b = s4[i * 2 + 1];
      short8 o;
      o[0] = (short)f2bf_rne(a.x); o[1] = (short)f2bf_rne(a.y);
      o[2] = (short)f2bf_rne(a.z); o[3] = (short)f2bf_rne(a.w);
      o[4] = (short)f2bf_rne(b.x); o[5] = (short)f2bf_rne(b.y);
      o[6] = (short)f2bf_rne(b.z); o[7] = (short)f2bf_rne(b.w);
      reinterpret_cast<short8*>(dst)[i] = o;
    }
    return;
  }
  // histogram block (n <= MAXN_HIST for this problem)
  for (int i = tid; i < n; i += blockDim.x) hcnt[i] = 0;
  for (int i = tid; i < npanel; i += blockDim.x) hflag[i] = 0;
  __syncthreads();
  for (int i = tid; i < n_new; i += blockDim.x) atomicAdd(&hcnt[new_idx[i]], 1);
  __syncthreads();
  for (int i = tid; i < n; i += blockDim.x) {
    int c = hcnt[i];
    cnt[i] = c;
    if (c) atomicOr(&hflag[i >> NPANEL_SHIFT], 1);
  }
  __syncthreads();
  for (int i = tid; i < npanel; i += blockDim.x) flags[i] = hflag[i];
  for (int i = tid; i < NSLOTS + 1; i += blockDim.x) misc[i] = 0.f;
}

// ---------- main fused GEMM + symmetric masked-reduction ----------
// Lower-triangle blocks only (bx<=by): each sim element s(r,c) is folded twice:
//   o1 (row r, col c, weight cnt[c])  — as before
//   o2 (row c, col r, weight cnt[r])  — mirror, skipped on diagonal blocks
// MFMA s(r,c) == s(c,r) bit-exact (same K-reduction over commuting products).
// K-loop = R4's measured-best schedule (3-buf ring, vmcnt(4), pinned order).
// NO device fences (R6: threadfence-per-thread caused a 5x regression).
__global__ __launch_bounds__(256) void simloss_kernel(
    const ushort* __restrict__ fb, const int* __restrict__ target,
    const int* __restrict__ cnt, const int* __restrict__ flags,
    float* __restrict__ misc, int d, int n_new, float alpha) {
  __shared__ __align__(16) ushort Als[3][BM * BK];
  __shared__ __align__(16) ushort Bls[3][BN * BK];
  __shared__ int   t_row[BM];
  __shared__ int   t_col[BN];
  __shared__ float cw_col[BN];
  __shared__ float cw_row[BM];
  __shared__ float red[4];

  const int bx = blockIdx.x, by = blockIdx.y;
  if (bx > by) return;                        // upper triangle: mirror handles it
  const int tid = threadIdx.x;
  const int rowBase = by * BM;
  const int colBase = bx * BN;
  const bool diag = (bx == by);

  // skip when BOTH orientations are provably zero
  if ((rowBase >= n_new && flags[bx] == 0) &&
      (colBase >= n_new && flags[by] == 0)) return;

  if (tid < BM) {
    t_row[tid]  = target[rowBase + tid];
    cw_row[tid] = (float)cnt[rowBase + tid];
  }
  if (tid < BN) {
    t_col[tid]  = target[colBase + tid];
    cw_col[tid] = (float)cnt[colBase + tid];
  }

  const int lane = tid & 63;
  const int wid  = tid >> 6;        // 4 waves, 2x2 grid of 64x64 wave tiles
  const int wr   = wid >> 1;
  const int wc   = wid & 1;
  const int l15  = lane & 15;
  const int kb   = lane >> 4;

  // staging: 512 16B-chunks per 128x32 tile; wave w issues chunks (2w+cc)*64+lane;
  // global source pre-swizzled with involution slot^=(row>>1)&3 (rule #21)
  const int ch0 = (wid * 2 + 0) * 64 + lane;
  const int ch1 = (wid * 2 + 1) * 64 + lane;
  const int r0 = ch0 >> 2, kq0 = (ch0 & 3) ^ ((ch0 >> 3) & 3);
  const int r1 = ch1 >> 2, kq1 = (ch1 & 3) ^ ((ch1 >> 3) & 3);
  const ushort* gA0 = fb + (size_t)(rowBase + r0) * d + kq0 * 8;
  const ushort* gA1 = fb + (size_t)(rowBase + r1) * d + kq1 * 8;
  const ushort* gB0 = fb + (size_t)(colBase + r0) * d + kq0 * 8;
  const ushort* gB1 = fb + (size_t)(colBase + r1) * d + kq1 * 8;
  const int lo0 = (wid * 2 + 0) * 512;
  const int lo1 = (wid * 2 + 1) * 512;

  f32x4 acc[4][4] = {};

  int aoff[4], boff[4];
#pragma unroll
  for (int m = 0; m < 4; ++m) {
    int row = wr * 64 + m * 16 + l15;
    aoff[m] = row * 32 + ((kb ^ ((row >> 1) & 3)) * 8);
  }
#pragma unroll
  for (int nf = 0; nf < 4; ++nf) {
    int row = wc * 64 + nf * 16 + l15;
    boff[nf] = row * 32 + ((kb ^ ((row >> 1) & 3)) * 8);
  }

  // drain metadata loads so manual vmcnt counts are exact
  asm volatile("s_waitcnt vmcnt(0) lgkmcnt(0)" ::: "memory");
  __builtin_amdgcn_sched_barrier(0);

  // prologue: stage tiles 0 and 1 (8 loads in flight)
  async_load16(gA0, &Als[0][lo0]);
  async_load16(gA1, &Als[0][lo1]);
  async_load16(gB0, &Bls[0][lo0]);
  async_load16(gB1, &Bls[0][lo1]);
  const int nk = d / BK;
  if (nk > 1) {
    async_load16(gA0 + BK, &Als[1][lo0]);
    async_load16(gA1 + BK, &Als[1][lo1]);
    async_load16(gB0 + BK, &Bls[1][lo0]);
    async_load16(gB1 + BK, &Bls[1][lo1]);
  }

  int cur = 0;
  for (int t = 0; t < nk; ++t) {
    if (t == nk - 1) asm volatile("s_waitcnt vmcnt(0)" ::: "memory");
    else             asm volatile("s_waitcnt vmcnt(4)" ::: "memory");
    __builtin_amdgcn_s_barrier();
    __builtin_amdgcn_sched_barrier(0);

    if (t + 2 < nk) {
      int nxt = cur + 2; if (nxt >= 3) nxt -= 3;
      int ko = (t + 2) * BK;
      async_load16(gA0 + ko, &Als[nxt][lo0]);
      async_load16(gA1 + ko, &Als[nxt][lo1]);
      async_load16(gB0 + ko, &Bls[nxt][lo0]);
      async_load16(gB1 + ko, &Bls[nxt][lo1]);
    }

    short8 afr[4], bfr[4];
#pragma unroll
    for (int m = 0; m < 4; ++m)
      afr[m] = *reinterpret_cast<const short8*>(&Als[cur][aoff[m]]);
#pragma unroll
    for (int nf = 0; nf < 4; ++nf)
      bfr[nf] = *reinterpret_cast<const short8*>(&Bls[cur][boff[nf]]);
    asm volatile("s_waitcnt lgkmcnt(0)" ::: "memory");
    __builtin_amdgcn_sched_barrier(0);

    // swapped operands: acc row = rowBase+wr*64+m*16+l15 (lane-fixed),
    // col = colBase+wc*64+nf*16+kb*4+q
#pragma unroll
    for (int m = 0; m < 4; ++m)
#pragma unroll
      for (int nf = 0; nf < 4; ++nf)
        acc[m][nf] = __builtin_amdgcn_mfma_f32_16x16x32_bf16(bfr[nf], afr[m], acc[m][nf], 0, 0, 0);

    cur = (cur + 1 == 3) ? 0 : cur + 1;
  }

  // ---- epilogue: fold both orientations into one scalar ----
  const float beta = 1.0f - alpha;
  int tc_r[4][4]; float cw_c[4][4]; bool cn_r[4][4];
#pragma unroll
  for (int nf = 0; nf < 4; ++nf)
#pragma unroll
    for (int q = 0; q < 4; ++q) {
      int cl = wc * 64 + nf * 16 + kb * 4 + q;
      tc_r[nf][q] = t_col[cl];
      cw_c[nf][q] = cw_col[cl];
      cn_r[nf][q] = (colBase + cl) < n_new;
    }

  const int  stale_row = n_new - 1;
  const bool blk_stale = (stale_row >= rowBase) && (stale_row < rowBase + BM);
  const int  srl = stale_row - rowBase;

  float tot = 0.f;
#pragma unroll
  for (int m = 0; m < 4; ++m) {
    int rl = wr * 64 + m * 16 + l15;
    int r  = rowBase + rl;
    int tr = t_row[rl];
    bool rnew = (r < n_new);
    float cwr  = cw_row[rl];
    float acwr = alpha * cwr;
    float bcwr = beta * cwr;
    float p = 0.f, ng = 0.f, t2 = 0.f;
#pragma unroll
    for (int nf = 0; nf < 4; ++nf)
#pragma unroll
      for (int q = 0; q < 4; ++q) {
        float s = acc[m][nf][q];
        bool same = (tr == tc_r[nf][q]);
        bool gm = (s > MARGIN);
        bool lp = (s < POS_THR);
        // o1: row r, col c, weight cnt[c]
        if (rnew) {
          if (same && lp) p  += cw_c[nf][q] * (1.0f - s);
          if (!same && gm) ng += s;
        } else {
          if (!same && gm) ng += cw_c[nf][q] * s;
        }
        // o2: row c, col r, weight cnt[r] (discarded on diag)
        if (cn_r[nf][q]) {
          if (same && lp)  t2 += acwr * (1.0f - s);
          if (!same && gm) t2 += beta * s;
        } else {
          if (!same && gm) t2 += bcwr * s;
        }
      }
    // stale row pos partial (o1 path covers it fully: o2 candidates have cnt=0)
    if (blk_stale && wr == (srl >> 6) && m == ((srl >> 4) & 3)) {
      float pr = p;
      pr += __shfl_xor(pr, 16); pr += __shfl_xor(pr, 32);
      if (lane < 16 && rl == srl) atomicAdd(&misc[NSLOTS], pr);
    }
    tot += rnew ? fmaf(alpha, p, beta * ng) : beta * ng;
    if (!diag) tot += t2;
  }
#pragma unroll
  for (int off = 32; off; off >>= 1) tot += __shfl_xor(tot, off);
  if (lane == 0) red[wid] = tot;
  __syncthreads();
  if (tid == 0)
    atomicAdd(&misc[(by * gridDim.x + bx) & (NSLOTS - 1)],
              red[0] + red[1] + red[2] + red[3]);
}

// ---------- finalize: 64 threads, read 257 floats ----------
__global__ void finalize_kernel(const float* __restrict__ misc,
                                float* __restrict__ out, int n, int n_new,
                                float alpha) {
  int t = threadIdx.x;
  float c = misc[t] + misc[t + 64] + misc[t + 128] + misc[t + 192];
#pragma unroll
  for (int off = 32; off; off >>= 1) c += __shfl_xor(c, off);
  if (t == 0)
    out[0] = (c + (float)(n - n_new) * alpha * misc[NSLOTS]) / (float)n;
}

// ---------- launch ----------
extern "C" void kernel_launch(void* const* d_in, const int* in_sizes, int n_in,
                              void* d_out, int out_size, void* d_ws, size_t ws_size,
                              hipStream_t stream) {
  const float* feature = (const float*)d_in[0];
  const int*   target  = (const int*)d_in[1];
  const int*   new_idx = (const int*)d_in[2];

  const int n     = in_sizes[1];
  const int d     = in_sizes[0] / n;
  const int n_new = in_sizes[2];
  const int n_old = (n_in > 3) ? in_sizes[3] : 0;
  const float alpha = (n_old != 0) ? 0.9f : 0.5f;
  const int npanel = n / BN;

  auto al = [](size_t x) { return (x + 255) & ~(size_t)255; };
  char* ws = (char*)d_ws;
  ushort* fb    = (ushort*)ws;
  size_t  off   = al((size_t)n * d * sizeof(ushort));
  int*    cnt   = (int*)(ws + off);   off += al((size_t)n * sizeof(int));
  int*    flags = (int*)(ws + off);   off += al((size_t)npanel * sizeof(int));
  float*  misc  = (float*)(ws + off);

  int total8 = (n * d) / 8;
  int convBlocks = (total8 + 255) / 256;
  prep_kernel<<<convBlocks + 1, 256, 0, stream>>>(feature, fb, new_idx, cnt, flags,
                                                  misc, total8, n, npanel,
                                                  n_new, convBlocks);

  dim3 grid(n / BN, n / BM);
  simloss_kernel<<<grid, 256, 0, stream>>>(fb, target, cnt, flags, misc,
                                           d, n_new, alpha);

  finalize_kernel<<<1, 64, 0, stream>>>(misc, (float*)d_out, n, n_new, alpha);
}

// Round 8
// 123.437 us; speedup vs baseline: 3.2498x; 1.0189x over previous
//
#include <hip/hip_runtime.h>
#include <hip/hip_bf16.h>
#include <stdint.h>

#define MARGIN   0.5f
#define POS_THR  (1.0f - 1e-5f)

typedef __attribute__((ext_vector_type(8))) short  short8;
typedef __attribute__((ext_vector_type(4))) float  f32x4;

#define BM 128
#define BN 128
#define BK 32
#define NSLOTS 256       // misc[0..255] partial sums, misc[256] = stale pos
#define MAXN_HIST 8192
#define NB 512           // persistent blocks: 2/CU x 256 CU, all co-resident

// ---------- helpers ----------
__device__ __forceinline__ ushort f2bf_rne(float x) {
  uint32_t u = __float_as_uint(x);
  u += 0x7fffu + ((u >> 16) & 1u);
  return (ushort)(u >> 16);
}

__device__ __forceinline__ void async_load16(const ushort* g, ushort* l) {
  // width-16 global->LDS DMA; LDS dest = wave-uniform base + lane*16B
  __builtin_amdgcn_global_load_lds(
      (__attribute__((address_space(1))) void*)(const_cast<ushort*>(g)),
      (__attribute__((address_space(3))) void*)(l),
      16, 0, 0);
}

#define WAITV(N) asm volatile("s_waitcnt vmcnt(" #N ")" ::: "memory")

// ---------- prep: convert blocks + ONE setup block (hist+meta+list) ----------
__global__ __launch_bounds__(256) void prep_kernel(
    const float* __restrict__ src, ushort* __restrict__ dst,
    const int* __restrict__ target, const int* __restrict__ new_idx,
    int2* __restrict__ metaG, int* __restrict__ list, int* __restrict__ nActG,
    float* __restrict__ misc, int total8, int n, int npanel, int n_new,
    int convBlocks) {
  const int tid = threadIdx.x;
  if ((int)blockIdx.x < convBlocks) {
    int i = blockIdx.x * blockDim.x + tid;
    if (i < total8) {
      const float4* s4 = reinterpret_cast<const float4*>(src);
      float4 a = s4[i * 2], b = s4[i * 2 + 1];
      short8 o;
      o[0] = (short)f2bf_rne(a.x); o[1] = (short)f2bf_rne(a.y);
      o[2] = (short)f2bf_rne(a.z); o[3] = (short)f2bf_rne(a.w);
      o[4] = (short)f2bf_rne(b.x); o[5] = (short)f2bf_rne(b.y);
      o[6] = (short)f2bf_rne(b.z); o[7] = (short)f2bf_rne(b.w);
      reinterpret_cast<short8*>(dst)[i] = o;
    }
    return;
  }
  // ---- setup block ----
  __shared__ int hcnt[MAXN_HIST];
  __shared__ int hflag[MAXN_HIST / BN];
  __shared__ int pcnt[256];
  for (int i = tid; i < n; i += 256) hcnt[i] = 0;
  for (int i = tid; i < npanel; i += 256) hflag[i] = 0;
  __syncthreads();
  for (int i = tid; i < n_new; i += 256) atomicAdd(&hcnt[new_idx[i]], 1);
  __syncthreads();
  for (int i = tid; i < n; i += 256) {
    int c = hcnt[i];
    metaG[i] = make_int2(target[i], __float_as_int((float)c));
    if (c) atomicOr(&hflag[i >> 7], 1);   // 128-wide panels
  }
  for (int i = tid; i < NSLOTS + 1; i += 256) misc[i] = 0.f;
  __syncthreads();
  // active-tile list over lower triangle bx<=by, deterministic compaction
  const int P  = npanel;
  const int TP = P * (P + 1) / 2;
  const int C  = (TP + 255) / 256;
  int l0 = tid * C, l1 = min(l0 + C, TP);
  int cnt_t = 0;
  int by = 0, bx = 0;
  if (l0 < TP) {
    by = (int)((sqrtf(8.f * (float)l0 + 1.f) - 1.f) * 0.5f);
    while ((by + 1) * (by + 2) / 2 <= l0) by++;
    while (by * (by + 1) / 2 > l0) by--;
    bx = l0 - by * (by + 1) / 2;
    int tby = by, tbx = bx;
    for (int l = l0; l < l1; ++l) {
      bool rowOld = tby * BM >= n_new, colOld = tbx * BN >= n_new;
      if (!((rowOld && hflag[tbx] == 0) && (colOld && hflag[tby] == 0))) cnt_t++;
      if (++tbx > tby) { tby++; tbx = 0; }
    }
  }
  pcnt[tid] = cnt_t;
  __syncthreads();
  for (int off = 1; off < 256; off <<= 1) {
    int v = (tid >= off) ? pcnt[tid - off] : 0;
    __syncthreads();
    pcnt[tid] += v;
    __syncthreads();
  }
  int pos = pcnt[tid] - cnt_t;
  if (tid == 255) *nActG = pcnt[255];
  if (l0 < TP) {
    for (int l = l0; l < l1; ++l) {
      bool rowOld = by * BM >= n_new, colOld = bx * BN >= n_new;
      if (!((rowOld && hflag[bx] == 0) && (colOld && hflag[by] == 0)))
        list[pos++] = (by << 16) | bx;
      if (++bx > by) { by++; bx = 0; }
    }
  }
}

// ---------- persistent fused GEMM + symmetric masked-reduction ----------
// 512 co-resident blocks grid-stride the active-tile list with ONE continuous
// 4-slot ring pipeline: step t+3 issued while computing step t (3-iter
// prefetch), static per-step vmcnt, metadata staged in-stream (all waves
// redundantly -> per-wave vmcnt uniform). Epilogue per tile is pure VALU.
__global__ __launch_bounds__(256, 2) void simloss_kernel(
    const ushort* __restrict__ fb, const int2* __restrict__ metaG,
    const int* __restrict__ list, const int* __restrict__ nActG,
    float* __restrict__ misc, int d, int n_new, float alpha) {
  __shared__ __align__(16) ushort Als[4][BM * BK];
  __shared__ __align__(16) ushort Bls[4][BN * BK];
  __shared__ __align__(16) int2  metaRl[2][BM];
  __shared__ __align__(16) int2  metaCl[2][BN];
  __shared__ float red[4];

  const int bid  = blockIdx.x;
  const int nAct = *nActG;
  if (bid >= nAct) return;

  const int tid  = threadIdx.x;
  const int lane = tid & 63;
  const int wid  = tid >> 6;
  const int wr   = wid >> 1;
  const int wc   = wid & 1;
  const int l15  = lane & 15;
  const int kb   = lane >> 4;
  const float beta = 1.0f - alpha;

  // staging lane geometry (R7-verified): chunk ch=(2w+cc)*64+lane,
  // r=ch>>2, src kq = (ch&3)^((r>>1)&3)  [pre-swizzled global source]
  const int ch0 = (wid * 2 + 0) * 64 + lane;
  const int ch1 = (wid * 2 + 1) * 64 + lane;
  const int r0 = ch0 >> 2, kq0 = (ch0 & 3) ^ ((ch0 >> 3) & 3);
  const int r1 = ch1 >> 2, kq1 = (ch1 & 3) ^ ((ch1 >> 3) & 3);
  const int lo0 = (wid * 2 + 0) * 512;
  const int lo1 = (wid * 2 + 1) * 512;

  // swizzled ds_read offsets (ushort units)
  int aoff[4], boff[4];
#pragma unroll
  for (int m = 0; m < 4; ++m) {
    int row = wr * 64 + m * 16 + l15;
    aoff[m] = row * 32 + ((kb ^ ((row >> 1) & 3)) * 8);
  }
#pragma unroll
  for (int nf = 0; nf < 4; ++nf) {
    int row = wc * 64 + nf * 16 + l15;
    boff[nf] = row * 32 + ((kb ^ ((row >> 1) & 3)) * 8);
  }

  int w  = bid;
  int pk = list[w];
  int curRow = (pk >> 16) * BM, curCol = (pk & 0xffff) * BN;
  const ushort* cA0 = fb + (size_t)(curRow + r0) * d + kq0 * 8;
  const ushort* cA1 = fb + (size_t)(curRow + r1) * d + kq1 * 8;
  const ushort* cB0 = fb + (size_t)(curCol + r0) * d + kq0 * 8;
  const ushort* cB1 = fb + (size_t)(curCol + r1) * d + kq1 * 8;
  const ushort* cMR = (const ushort*)(metaG + curRow) + (size_t)lane * 8;
  const ushort* cMC = (const ushort*)(metaG + curCol) + (size_t)lane * 8;

  f32x4 acc[4][4] = {};
  float tot = 0.f;
  int mp = 0;

  // clean counters, then prologue: issue steps 0(+meta),1,2 of tile 0
  asm volatile("s_waitcnt vmcnt(0) lgkmcnt(0)" ::: "memory");
  __builtin_amdgcn_sched_barrier(0);
#define STAGE4(pa0, pa1, pb0, pb1, p)                                          \
  { async_load16((pa0) + (p) * BK, &Als[(p) & 3][lo0]);                        \
    async_load16((pa1) + (p) * BK, &Als[(p) & 3][lo1]);                        \
    async_load16((pb0) + (p) * BK, &Bls[(p) & 3][lo0]);                        \
    async_load16((pb1) + (p) * BK, &Bls[(p) & 3][lo1]); }
  STAGE4(cA0, cA1, cB0, cB1, 0);
  async_load16(cMR, (ushort*)&metaRl[0][0]);
  async_load16(cMC, (ushort*)&metaCl[0][0]);
  STAGE4(cA0, cA1, cB0, cB1, 1);
  STAGE4(cA0, cA1, cB0, cB1, 2);

  for (;;) {
    const bool hasNext = (w + NB) < nAct;
    const int  pkN = hasNext ? list[w + NB] : pk;
    const int  nxtRow = (pkN >> 16) * BM, nxtCol = (pkN & 0xffff) * BN;
    const ushort* nA0 = fb + (size_t)(nxtRow + r0) * d + kq0 * 8;
    const ushort* nA1 = fb + (size_t)(nxtRow + r1) * d + kq1 * 8;
    const ushort* nB0 = fb + (size_t)(nxtCol + r0) * d + kq0 * 8;
    const ushort* nB1 = fb + (size_t)(nxtCol + r1) * d + kq1 * 8;
    const ushort* nMR = (const ushort*)(metaG + nxtRow) + (size_t)lane * 8;
    const ushort* nMC = (const ushort*)(metaG + nxtCol) + (size_t)lane * 8;

#pragma unroll
    for (int i = 0; i < 8; ++i) {
      // wait: steps <= t done. outstanding = L(t+1)+L(t+2); L=6 on tile step 0
      if (i < 6)        WAITV(8);
      else if (i == 6)  { if (hasNext) WAITV(10); else WAITV(4); }
      else              { if (hasNext) WAITV(10); else WAITV(0); }
      __builtin_amdgcn_s_barrier();
      __builtin_amdgcn_sched_barrier(0);

      // issue step t+3
      if (i <= 4) {
        STAGE4(cA0, cA1, cB0, cB1, i + 3);
      } else if (hasNext) {
        if (i == 5) {
          STAGE4(nA0, nA1, nB0, nB1, 0);
          async_load16(nMR, (ushort*)&metaRl[mp ^ 1][0]);
          async_load16(nMC, (ushort*)&metaCl[mp ^ 1][0]);
        } else if (i == 6) {
          STAGE4(nA0, nA1, nB0, nB1, 1);
        } else {
          STAGE4(nA0, nA1, nB0, nB1, 2);
        }
      }

      // compute step t from ring slot i&3
      short8 afr[4], bfr[4];
      const ushort* As = &Als[i & 3][0];
      const ushort* Bs = &Bls[i & 3][0];
#pragma unroll
      for (int m = 0; m < 4; ++m)
        afr[m] = *reinterpret_cast<const short8*>(&As[aoff[m]]);
#pragma unroll
      for (int nf = 0; nf < 4; ++nf)
        bfr[nf] = *reinterpret_cast<const short8*>(&Bs[boff[nf]]);
      asm volatile("s_waitcnt lgkmcnt(0)" ::: "memory");
      __builtin_amdgcn_sched_barrier(0);

      // swapped operands: acc row = curRow+wr*64+m*16+l15 (lane-fixed),
      // col = curCol+wc*64+nf*16+kb*4+q
#pragma unroll
      for (int m = 0; m < 4; ++m)
#pragma unroll
        for (int nf = 0; nf < 4; ++nf)
          acc[m][nf] = __builtin_amdgcn_mfma_f32_16x16x32_bf16(bfr[nf], afr[m], acc[m][nf], 0, 0, 0);
    }

    // ---- tile epilogue: pure VALU fold (both orientations) ----
    {
      const bool diag = (curRow == curCol);
      int tcr[4][4]; float cwc[4][4]; bool cnr[4][4];
#pragma unroll
      for (int nf = 0; nf < 4; ++nf)
#pragma unroll
        for (int q = 0; q < 4; ++q) {
          int cl = wc * 64 + nf * 16 + kb * 4 + q;
          int2 mc = metaCl[mp][cl];
          tcr[nf][q] = mc.x;
          cwc[nf][q] = __int_as_float(mc.y);
          cnr[nf][q] = (curCol + cl) < n_new;
        }
      const int  stale_row = n_new - 1;
      const bool blk_stale = (stale_row >= curRow) && (stale_row < curRow + BM);
      const int  srl = stale_row - curRow;
#pragma unroll
      for (int m = 0; m < 4; ++m) {
        int rl = wr * 64 + m * 16 + l15;
        int r  = curRow + rl;
        int2 mr = metaRl[mp][rl];
        int   tr  = mr.x;
        float cwr = __int_as_float(mr.y);
        bool rnew = (r < n_new);
        float acwr = alpha * cwr, bcwr = beta * cwr;
        float p = 0.f, ng = 0.f, t2 = 0.f;
#pragma unroll
        for (int nf = 0; nf < 4; ++nf)
#pragma unroll
          for (int q = 0; q < 4; ++q) {
            float s = acc[m][nf][q];
            bool same = (tr == tcr[nf][q]);
            bool gm = (s > MARGIN);
            bool lp = (s < POS_THR);
            if (rnew) {                       // o1: row r, col c, weight cnt[c]
              if (same && lp)  p  += cwc[nf][q] * (1.0f - s);
              if (!same && gm) ng += s;
            } else {
              if (!same && gm) ng += cwc[nf][q] * s;
            }
            if (cnr[nf][q]) {                 // o2: row c, col r, weight cnt[r]
              if (same && lp)  t2 += acwr * (1.0f - s);
              if (!same && gm) t2 += beta * s;
            } else {
              if (!same && gm) t2 += bcwr * s;
            }
          }
        if (blk_stale && wr == (srl >> 6) && m == ((srl >> 4) & 3)) {
          float pr = p;
          pr += __shfl_xor(pr, 16); pr += __shfl_xor(pr, 32);
          if (lane < 16 && rl == srl) atomicAdd(&misc[NSLOTS], pr);
        }
        tot += rnew ? fmaf(alpha, p, beta * ng) : beta * ng;
        if (!diag) tot += t2;
        acc[m][0] = f32x4{}; acc[m][1] = f32x4{};
        acc[m][2] = f32x4{}; acc[m][3] = f32x4{};
      }
    }

    if (!hasNext) break;
    w += NB; pk = pkN; mp ^= 1;
    curRow = nxtRow; curCol = nxtCol;
    cA0 = nA0; cA1 = nA1; cB0 = nB0; cB1 = nB1;
  }

  // ---- one atomic per block ----
#pragma unroll
  for (int off = 32; off; off >>= 1) tot += __shfl_xor(tot, off);
  if (lane == 0) red[wid] = tot;
  __syncthreads();
  if (tid == 0)
    atomicAdd(&misc[bid & (NSLOTS - 1)], red[0] + red[1] + red[2] + red[3]);
}

// ---------- finalize: 64 threads, read 257 floats ----------
__global__ void finalize_kernel(const float* __restrict__ misc,
                                float* __restrict__ out, int n, int n_new,
                                float alpha) {
  int t = threadIdx.x;
  float c = misc[t] + misc[t + 64] + misc[t + 128] + misc[t + 192];
#pragma unroll
  for (int off = 32; off; off >>= 1) c += __shfl_xor(c, off);
  if (t == 0)
    out[0] = (c + (float)(n - n_new) * alpha * misc[NSLOTS]) / (float)n;
}

// ---------- launch ----------
extern "C" void kernel_launch(void* const* d_in, const int* in_sizes, int n_in,
                              void* d_out, int out_size, void* d_ws, size_t ws_size,
                              hipStream_t stream) {
  const float* feature = (const float*)d_in[0];
  const int*   target  = (const int*)d_in[1];
  const int*   new_idx = (const int*)d_in[2];

  const int n     = in_sizes[1];
  const int d     = in_sizes[0] / n;
  const int n_new = in_sizes[2];
  const int n_old = (n_in > 3) ? in_sizes[3] : 0;
  const float alpha = (n_old != 0) ? 0.9f : 0.5f;
  const int npanel = n / BN;
  const int maxTiles = npanel * (npanel + 1) / 2;

  auto al = [](size_t x) { return (x + 255) & ~(size_t)255; };
  char* ws = (char*)d_ws;
  ushort* fb    = (ushort*)ws;
  size_t  off   = al((size_t)n * d * sizeof(ushort));
  int2*   metaG = (int2*)(ws + off);  off += al((size_t)n * sizeof(int2));
  int*    list  = (int*)(ws + off);   off += al((size_t)maxTiles * sizeof(int));
  int*    nAct  = (int*)(ws + off);   off += al(sizeof(int));
  float*  misc  = (float*)(ws + off);

  int total8 = (n * d) / 8;
  int convBlocks = (total8 + 255) / 256;
  prep_kernel<<<convBlocks + 1, 256, 0, stream>>>(feature, fb, target, new_idx,
                                                  metaG, list, nAct, misc,
                                                  total8, n, npanel, n_new,
                                                  convBlocks);

  simloss_kernel<<<NB, 256, 0, stream>>>(fb, metaG, list, nAct, misc,
                                         d, n_new, alpha);

  finalize_kernel<<<1, 64, 0, stream>>>(misc, (float*)d_out, n, n_new, alpha);
}